// Round 3
// baseline (139.099 us; speedup 1.0000x reference)
//
#include <hip/hip_runtime.h>
#include <math.h>

// Problem constants (from reference setup): B=4, T=512, Z=32, C=3*Z=96.
#define BB 4
#define TT 512
#define ZZ 32
#define CC 96
#define NSLICE (BB * ZZ)   // 128

// Native clang vector (works with __builtin_nontemporal_store, unlike HIP float4).
typedef float vf4 __attribute__((ext_vector_type(4)));

// lower[i,j] = (-1)^(i-j) * exp2(L[i]-L[j]) / d_i  for j<=i, else 0
//   d_t = mapped[b,t,32+2z] + 1,  s_t = mapped[b,t,33+2z]
//   L[t] = sum_{k<t} log2(s_k/d_k)   (clamped at -200 per term; still underflows
//                                     exp2 to exact 0 in fp32, matching the
//                                     reference's where(isfinite, ., 0))

// Kernel 1: per (b,z) slice: write mapped_mean, compute dinv[] and prefix L[].
// Wave-shuffle inclusive scan (8 waves of 64) + one LDS round for wave offsets.
__global__ __launch_bounds__(512) void prep_kernel(const float* __restrict__ mapped,
                                                   float* __restrict__ out_mean,
                                                   float* __restrict__ dinv,
                                                   float* __restrict__ Lpre) {
    const int slice = blockIdx.x;      // b*32 + z
    const int b = slice >> 5;
    const int z = slice & 31;
    const int t = threadIdx.x;

    const float* row = mapped + ((size_t)b * TT + t) * CC;
    const float meanv = row[z];
    const float dval  = row[ZZ + 2 * z] + 1.0f;
    const float sval  = (t < TT - 1) ? row[ZZ + 2 * z + 1] : 0.0f;

    out_mean[slice * TT + t] = meanv;
    const float di = 1.0f / dval;
    dinv[slice * TT + t] = di;

    float g = 0.0f;
    if (t < TT - 1) g = fmaxf(log2f(sval * di), -200.0f);

    // Inclusive scan within each 64-lane wave.
    const int lane = t & 63;
    const int wid  = t >> 6;          // 0..7
    float v = g;
    #pragma unroll
    for (int off = 1; off < 64; off <<= 1) {
        float n = __shfl_up(v, off, 64);
        if (lane >= off) v += n;
    }
    __shared__ float wsum[8];
    if (lane == 63) wsum[wid] = v;
    __syncthreads();
    float offv = 0.0f;
    #pragma unroll
    for (int w = 0; w < 8; ++w)
        if (w < wid) offv += wsum[w];
    const float incl = v + offv;       // sum_{k<=t} g_k
    Lpre[slice * TT + t] = incl - g;   // exclusive prefix: sum_{k<t} g_k
}

// Kernel 2: fill cov_tril_lower. One vf4 (4 consecutive cols of one row)
// per thread; raw v_exp_f32; branch-free sign/zero; nontemporal stores.
__global__ __launch_bounds__(256) void fill_kernel(const float* __restrict__ dinv,
                                                   const float* __restrict__ Lpre,
                                                   float* __restrict__ out_tril) {
    const int gid = blockIdx.x * 256 + threadIdx.x;  // vf4 index
    const int slice = gid >> 16;                     // 65536 vf4 per slice
    const int rem = gid & 65535;
    const int i  = rem >> 7;                         // row (128 vf4 per row)
    const int j4 = (rem & 127) << 2;                 // first column of this vf4

    const float* Ls = Lpre + (slice << 9);
    const float Li = Ls[i];
    const float di = dinv[(slice << 9) + i];
    const vf4 Lj = *reinterpret_cast<const vf4*>(Ls + j4);

    // parity of (i - j): j4 is a multiple of 4, so base parity = i&1,
    // alternating across the 4 lanes of the vf4.
    const int p0 = i & 1;

    vf4 o;
    {
        float r = __builtin_amdgcn_exp2f(Li - Lj.x) * di;
        r = p0 ? -r : r;
        o.x = (j4 + 0 <= i) ? r : 0.0f;
    }
    {
        float r = __builtin_amdgcn_exp2f(Li - Lj.y) * di;
        r = p0 ? r : -r;
        o.y = (j4 + 1 <= i) ? r : 0.0f;
    }
    {
        float r = __builtin_amdgcn_exp2f(Li - Lj.z) * di;
        r = p0 ? -r : r;
        o.z = (j4 + 2 <= i) ? r : 0.0f;
    }
    {
        float r = __builtin_amdgcn_exp2f(Li - Lj.w) * di;
        r = p0 ? r : -r;
        o.w = (j4 + 3 <= i) ? r : 0.0f;
    }
    __builtin_nontemporal_store(o, reinterpret_cast<vf4*>(out_tril) + gid);
}

extern "C" void kernel_launch(void* const* d_in, const int* in_sizes, int n_in,
                              void* d_out, int out_size, void* d_ws, size_t ws_size,
                              hipStream_t stream) {
    const float* mapped = (const float*)d_in[0];
    float* out = (float*)d_out;

    float* out_mean = out;                          // 4*32*512 = 65536 floats
    float* out_tril = out + NSLICE * TT;            // 4*32*512*512 floats

    float* dinv = (float*)d_ws;                     // 65536 floats (256 KB)
    float* Lpre = dinv + NSLICE * TT;               // 65536 floats (256 KB)

    prep_kernel<<<NSLICE, TT, 0, stream>>>(mapped, out_mean, dinv, Lpre);

    const int n_f4 = NSLICE * TT * TT / 4;          // 8,388,608 vf4
    fill_kernel<<<n_f4 / 256, 256, 0, stream>>>(dinv, Lpre, out_tril);
}

// Round 4
// 134.483 us; speedup vs baseline: 1.0343x; 1.0343x over previous
//
#include <hip/hip_runtime.h>
#include <math.h>

// Problem constants (from reference setup): B=4, T=512, Z=32, C=3*Z=96.
#define BB 4
#define TT 512
#define ZZ 32
#define CC 96
#define NSLICE (BB * ZZ)   // 128

typedef float vf4 __attribute__((ext_vector_type(4)));

// lower[i,j] = (-1)^(i-j) * exp2(L[i]-L[j]) / d_i  for j<=i, else 0
//   d_t = mapped[b,t,32+2z] + 1,  s_t = mapped[b,t,33+2z]
//   L[t] = sum_{k<t} log2(s_k/d_k)   (clamped at -200 per term; still underflows
//                                     exp2 to exact 0 in fp32, matching the
//                                     reference's where(isfinite, ., 0))

// Kernel 1: per (b,z) slice: write mapped_mean, compute dinv[] and prefix L[].
__global__ __launch_bounds__(512) void prep_kernel(const float* __restrict__ mapped,
                                                   float* __restrict__ out_mean,
                                                   float* __restrict__ dinv,
                                                   float* __restrict__ Lpre) {
    const int slice = blockIdx.x;      // b*32 + z
    const int b = slice >> 5;
    const int z = slice & 31;
    const int t = threadIdx.x;

    const float* row = mapped + ((size_t)b * TT + t) * CC;
    const float meanv = row[z];
    const float dval  = row[ZZ + 2 * z] + 1.0f;
    const float sval  = (t < TT - 1) ? row[ZZ + 2 * z + 1] : 0.0f;

    out_mean[slice * TT + t] = meanv;
    const float di = 1.0f / dval;
    dinv[slice * TT + t] = di;

    float g = 0.0f;
    if (t < TT - 1) g = fmaxf(log2f(sval * di), -200.0f);

    // Inclusive scan within each 64-lane wave, then cross-wave via LDS.
    const int lane = t & 63;
    const int wid  = t >> 6;          // 0..7
    float v = g;
    #pragma unroll
    for (int off = 1; off < 64; off <<= 1) {
        float n = __shfl_up(v, off, 64);
        if (lane >= off) v += n;
    }
    __shared__ float wsum[8];
    if (lane == 63) wsum[wid] = v;
    __syncthreads();
    float offv = 0.0f;
    #pragma unroll
    for (int w = 0; w < 8; ++w)
        if (w < wid) offv += wsum[w];
    const float incl = v + offv;       // sum_{k<=t} g_k
    Lpre[slice * TT + t] = incl - g;   // exclusive prefix: sum_{k<t} g_k
}

// Kernel 2: fill cov_tril_lower. One vf4 (4 consecutive cols of one row) per
// thread; raw v_exp_f32; sign folded into +/-dinv; ordinary cached stores
// (same write path the 6.3 TB/s harness memset uses).
__global__ __launch_bounds__(256) void fill_kernel(const float* __restrict__ dinv,
                                                   const float* __restrict__ Lpre,
                                                   float* __restrict__ out_tril) {
    const int gid = blockIdx.x * 256 + threadIdx.x;  // vf4 index
    const int slice = gid >> 16;                     // 65536 vf4 per slice
    const int rem = gid & 65535;
    const int i  = rem >> 7;                         // row (128 vf4 per row)
    const int j4 = (rem & 127) << 2;                 // first column of this vf4

    const float* Ls = Lpre + (slice << 9);
    const float Li = Ls[i];
    const float di = dinv[(slice << 9) + i];
    const vf4 Lj = *reinterpret_cast<const vf4*>(Ls + j4);

    // sign(i-j): j4 % 4 == 0 so lane-0 parity = i&1, alternating across lanes.
    const float a = (i & 1) ? -di : di;   // sign for even lane offsets (x, z)
    const float bsg = -a;                 // sign for odd lane offsets  (y, w)

    vf4 o;
    o.x = (j4 + 0 <= i) ? __builtin_amdgcn_exp2f(Li - Lj.x) * a   : 0.0f;
    o.y = (j4 + 1 <= i) ? __builtin_amdgcn_exp2f(Li - Lj.y) * bsg : 0.0f;
    o.z = (j4 + 2 <= i) ? __builtin_amdgcn_exp2f(Li - Lj.z) * a   : 0.0f;
    o.w = (j4 + 3 <= i) ? __builtin_amdgcn_exp2f(Li - Lj.w) * bsg : 0.0f;

    *(reinterpret_cast<vf4*>(out_tril) + gid) = o;
}

extern "C" void kernel_launch(void* const* d_in, const int* in_sizes, int n_in,
                              void* d_out, int out_size, void* d_ws, size_t ws_size,
                              hipStream_t stream) {
    const float* mapped = (const float*)d_in[0];
    float* out = (float*)d_out;

    float* out_mean = out;                          // 4*32*512 = 65536 floats
    float* out_tril = out + NSLICE * TT;            // 4*32*512*512 floats

    float* dinv = (float*)d_ws;                     // 65536 floats (256 KB)
    float* Lpre = dinv + NSLICE * TT;               // 65536 floats (256 KB)

    prep_kernel<<<NSLICE, TT, 0, stream>>>(mapped, out_mean, dinv, Lpre);

    const int n_f4 = NSLICE * TT * TT / 4;          // 8,388,608 vf4
    fill_kernel<<<n_f4 / 256, 256, 0, stream>>>(dinv, Lpre, out_tril);
}